// Round 8
// baseline (349.126 us; speedup 1.0000x reference)
//
#include <hip/hip_runtime.h>
#include <cstdint>

#define BN_EPS 1e-5f

typedef unsigned int uint;
typedef unsigned short u16;

// ---------------------------------------------------------------------------
// x:  (32, 256, 28, 28) f32
// w1: (1024, 256, 3, 3)  conv1: 256 -> 1024 (groups collapse: same input)
// w2: (1024, 256, 3, 3)  conv2: grouped x4
// out: (32, 256, 28, 28) f32
// Packing: 256 ch -> 8 u32 words; bit (c%32) of word (c/32) = (v>=0)
// Weights packed [half][tap][1024 oc][4 words].
//
// r8 structure: conv2 is made conv1-shaped (the 2x-faster shape):
//   kConv2a: block=(g,ytile,b), weights fully register-resident (NO reloads),
//            3.8KB LDS group slice, emits raw u16 popcount partial S per
//            (g,oc,pix) + per-(g,pix) 3x3 box-sum BS (from its prologue).
//   kRed:    out = relu(xin + sum_g(2*inv*S - inv*BS + bb)); LDS transpose
//            so P reads AND out writes stay coalesced.
// Batch in 2 chunks of 16 so P16 = 25.7MB (ws ~31MB total).
// NOTE (r5): __launch_bounds__ 2nd arg is waves/SIMD on CDNA; (256,4)
// capped VGPR at 64 and spilled 6.3 GB. Leave it unconstrained.
// ---------------------------------------------------------------------------

__global__ __launch_bounds__(256) void kPrep(
    const float* __restrict__ s1, const float* __restrict__ b1,
    const float* __restrict__ m1, const float* __restrict__ v1,
    const float* __restrict__ s2, const float* __restrict__ b2,
    const float* __restrict__ m2, const float* __restrict__ v2,
    const float* __restrict__ lam,
    float* __restrict__ bnA1, float* __restrict__ bnB1,
    float* __restrict__ bnA2, float* __restrict__ bbSum) {
  int t = blockIdx.x * 256 + threadIdx.x;
  if (t >= 1024) return;
  float inv1 = s1[t] / sqrtf(v1[t] + BN_EPS);
  bnA1[t] = inv1;
  bnB1[t] = b1[t] - m1[t] * inv1;
  float inv2 = s2[t] / sqrtf(v2[t] + BN_EPS);
  bnA2[t] = inv2 * lam[t >> 8];
  if (t < 256) {
    float s = 0.0f;
#pragma unroll
    for (int g = 0; g < 4; g++) {
      int idx = g * 256 + t;
      float inv = s2[idx] / sqrtf(v2[idx] + BN_EPS);
      s += (b2[idx] - m2[idx] * inv) * lam[g];
    }
    bbSum[t] = s;
  }
}

// Each lane reads one full 64B line (16 consecutive px of its channel),
// then 16 ballots pack channel bits.
__global__ __launch_bounds__(256) void kPackX(const float* __restrict__ x,
                                              uint* __restrict__ A1p) {
  const int tid = threadIdx.x;
  const int lane = tid & 63, cb = tid >> 6;
  const int grp = blockIdx.x;  // 0..1567 = 32 b * 49 groups of 16 px
  const int b = grp / 49, r16 = (grp % 49) * 16;
  const float4* src = (const float4*)(x + ((b * 256 + cb * 64 + lane) * 784 + r16));
  float4 f0 = src[0], f1 = src[1], f2 = src[2], f3 = src[3];
  uint* outp = A1p + (b * 784 + r16) * 8 + cb * 2;
#define PB(V, PX) { unsigned long long m = __ballot((V) >= 0.0f); \
    if (lane == 0) { outp[(PX)*8] = (uint)m; outp[(PX)*8+1] = (uint)(m>>32); } }
  PB(f0.x, 0)  PB(f0.y, 1)  PB(f0.z, 2)  PB(f0.w, 3)
  PB(f1.x, 4)  PB(f1.y, 5)  PB(f1.z, 6)  PB(f1.w, 7)
  PB(f2.x, 8)  PB(f2.y, 9)  PB(f2.z, 10) PB(f2.w, 11)
  PB(f3.x, 12) PB(f3.y, 13) PB(f3.z, 14) PB(f3.w, 15)
#undef PB
}

// Pack weight sign bits, layout [half][tap][1024 oc][4 words]
__global__ __launch_bounds__(256) void kPackW(const float* __restrict__ w,
                                              uint* __restrict__ Wp) {
  int wg = blockIdx.x * 4 + (threadIdx.x >> 6);
  int lane = threadIdx.x & 63;
  int oc = wg / 36;
  int r = wg - oc * 36;
  int tap = r >> 2;
  int cb = r & 3;  // 64-ch block; half = cb>>1, words (cb&1)*2, +1
  float v = w[(oc * 256 + cb * 64 + lane) * 9 + tap];
  unsigned long long m = __ballot(v >= 0.0f);
  if (lane == 0) {
    uint* dst = Wp + (((cb >> 1) * 9 + tap) * 1024 + oc) * 4 + (cb & 1) * 2;
    dst[0] = (uint)m;
    dst[1] = (uint)(m >> 32);
  }
}

// ---------------- conv1: padded LDS + columns + 2 y-rows -------------------
// block = 256 (4 waves = oc chunks); grid (4 quad, 14 ytile, 32 b)

#define XP8(A0, A1, WP) (__popc((A0).x ^ (WP)[0]) + __popc((A0).y ^ (WP)[1]) + \
                         __popc((A0).z ^ (WP)[2]) + __popc((A0).w ^ (WP)[3]) + \
                         __popc((A1).x ^ (WP)[4]) + __popc((A1).y ^ (WP)[5]) + \
                         __popc((A1).z ^ (WP)[6]) + __popc((A1).w ^ (WP)[7]))

#define COL1(P, D0, D1, D2, EMIT, X, THR) { \
  const uint4* ap = abase + (P) * 2; \
  int q0 = 0, q1 = 0, q2 = 0; \
  { uint4 ra = ap[0],   rb = ap[1]; \
    if (D0) q0 += XP8(ra, rb, wr + 0);  if (D1) q1 += XP8(ra, rb, wr + 8); \
    if (D2) q2 += XP8(ra, rb, wr + 16); } \
  { uint4 ra = ap[60],  rb = ap[61]; \
    if (D0) q0 += XP8(ra, rb, wr + 24); if (D1) q1 += XP8(ra, rb, wr + 32); \
    if (D2) q2 += XP8(ra, rb, wr + 40); } \
  { uint4 ra = ap[120], rb = ap[121]; \
    if (D0) q0 += XP8(ra, rb, wr + 48); if (D1) q1 += XP8(ra, rb, wr + 56); \
    if (D2) q2 += XP8(ra, rb, wr + 64); } \
  if (EMIT) { int Sx = a0 + q2; \
    unsigned long long m = __ballot((float)Sx < (THR)); \
    if (lane == 0) { outp[(X) * 32] = (uint)m; outp[(X) * 32 + 1] = (uint)(m >> 32); } } \
  a0 = a1 + q1; a1 = q0; }

__global__ __launch_bounds__(256) void kConv1(
    const uint* __restrict__ A1p, const uint* __restrict__ W1p,
    const float* __restrict__ bnA1, const float* __restrict__ bnB1,
    uint* __restrict__ A2p) {
  const int tid = threadIdx.x;
  const int lane = tid & 63;
  const int quad = blockIdx.x, ytile = blockIdx.y, b = blockIdx.z;
  const int y0 = ytile * 2;
  const int chunk = quad * 4 + (tid >> 6);
  const int oc = chunk * 64 + lane;

  __shared__ uint apad[960];  // [4 rows][30 cols][8 words], zero padded
  { uint4* z = (uint4*)apad;
    if (tid < 240) z[tid] = make_uint4(0u, 0u, 0u, 0u); }
  __syncthreads();
  if (tid < 224) {  // 4 rows x 56 uint4
    int r = tid / 56, idx = tid - r * 56;
    int ry = y0 - 1 + r;
    if (ry >= 0 && ry < 28) {
      ((uint4*)apad)[r * 60 + 2 + idx] =
          ((const uint4*)(A1p + (b * 784 + ry * 28) * 8))[idx];
    }
  }
  __syncthreads();

  uint wr[72];
  const uint4* wb = ((const uint4*)W1p) + oc;
#pragma unroll
  for (int t = 0; t < 9; t++) {
    uint4 w0 = wb[t * 1024];         // half0
    uint4 w1 = wb[(9 + t) * 1024];   // half1
    wr[t*8+0] = w0.x; wr[t*8+1] = w0.y; wr[t*8+2] = w0.z; wr[t*8+3] = w0.w;
    wr[t*8+4] = w1.x; wr[t*8+5] = w1.y; wr[t*8+6] = w1.z; wr[t*8+7] = w1.w;
  }
  int pw[9];
#pragma unroll
  for (int t9 = 0; t9 < 9; t9++) {
    int s = 0;
#pragma unroll
    for (int i = 0; i < 8; i++) s += __popc(wr[t9*8 + i]);
    pw[t9] = s;
  }
  const float inv = bnA1[oc], bb = bnB1[oc];
  const float tneg = -bb / inv;  // bn1_scale >= 0 -> inv >= 0

  for (int yy = 0; yy < 2; yy++) {
    const int y = y0 + yy;
    const int ytop = (y > 0) ? 1 : 0, ybot = (y < 27) ? 1 : 0;
    const int nrv = 1 + ytop + ybot;
    int pwInvRow = 0;
    if (!ytop) pwInvRow += pw[0] + pw[1] + pw[2];
    if (!ybot) pwInvRow += pw[6] + pw[7] + pw[8];
    int pwV0 = pw[3], pwV2 = pw[5];
    if (ytop) { pwV0 += pw[0]; pwV2 += pw[2]; }
    if (ybot) { pwV0 += pw[6]; pwV2 += pw[8]; }
    const float thrM  = ((float)(256 * 3 * nrv + 2 * pwInvRow) - tneg) * 0.5f;
    const float thr0  = ((float)(256 * 2 * nrv + 2 * (pwInvRow + pwV0)) - tneg) * 0.5f;
    const float thr27 = ((float)(256 * 2 * nrv + 2 * (pwInvRow + pwV2)) - tneg) * 0.5f;

    uint* outp = A2p + (b * 784 + y * 28) * 32 + chunk * 2;
    const uint4* abase = ((const uint4*)apad) + yy * 60;
    int a0 = 0, a1 = 0;
    COL1(0, 1, 0, 0, 0, 0, 0.0f)
    COL1(1, 1, 1, 0, 0, 0, 0.0f)
    COL1(2, 1, 1, 1, 1, 0, thr0)
    for (int p = 3; p <= 24; p += 3) {  // rolled: cols 3..26, emits x=1..24
      COL1(p,     1, 1, 1, 1, (p - 2), thrM)
      COL1(p + 1, 1, 1, 1, 1, (p - 1), thrM)
      COL1(p + 2, 1, 1, 1, 1, (p),     thrM)
    }
    COL1(27, 1, 1, 1, 1, 25, thrM)
    COL1(28, 0, 1, 1, 1, 26, thrM)
    COL1(29, 0, 0, 1, 1, 27, thr27)
  }
}

// ---------------- conv2a: conv1-shaped, per-group u16 partials -------------
// block = (g, ytile, b-chunk); 4 waves = 4 oc-chunks of 64 within group g.
// Weights fully register-resident; emits S (raw AND-popcount sum) as u16.

#define AP8(A0, A1, WP) (__popc((A0).x & (WP)[0]) + __popc((A0).y & (WP)[1]) + \
                         __popc((A0).z & (WP)[2]) + __popc((A0).w & (WP)[3]) + \
                         __popc((A1).x & (WP)[4]) + __popc((A1).y & (WP)[5]) + \
                         __popc((A1).z & (WP)[6]) + __popc((A1).w & (WP)[7]))

#define COLA(P, D0, D1, D2, EMIT, X) { \
  const uint4* ap = abase + (P) * 2; \
  int q0 = 0, q1 = 0, q2 = 0; \
  { uint4 ra = ap[0],   rb = ap[1]; \
    if (D0) q0 += AP8(ra, rb, wr + 0);  if (D1) q1 += AP8(ra, rb, wr + 8); \
    if (D2) q2 += AP8(ra, rb, wr + 16); } \
  { uint4 ra = ap[60],  rb = ap[61]; \
    if (D0) q0 += AP8(ra, rb, wr + 24); if (D1) q1 += AP8(ra, rb, wr + 32); \
    if (D2) q2 += AP8(ra, rb, wr + 40); } \
  { uint4 ra = ap[120], rb = ap[121]; \
    if (D0) q0 += AP8(ra, rb, wr + 48); if (D1) q1 += AP8(ra, rb, wr + 56); \
    if (D2) q2 += AP8(ra, rb, wr + 64); } \
  if (EMIT) { int Sx = a0 + q2; Pp[(X) * 1024] = (u16)Sx; } \
  a0 = a1 + q1; a1 = q0; }

__global__ __launch_bounds__(256) void kConv2a(
    const uint* __restrict__ A2p, const uint* __restrict__ W2p,
    u16* __restrict__ P16, float* __restrict__ BSf, int b0) {
  const int tid = threadIdx.x;
  const int lane = tid & 63;
  const int g = blockIdx.x, ytile = blockIdx.y, bb = blockIdx.z;
  const int b = b0 + bb;
  const int y0 = ytile * 2;
  const int oc = g * 256 + (tid >> 6) * 64 + lane;

  __shared__ uint apad[960];  // [4 rows][30 cols][8 words] (group g slice)
  __shared__ int sp[120];     // [4 rows][30 cols] popcounts

  { uint4* z = (uint4*)apad;
    if (tid < 240) z[tid] = make_uint4(0u, 0u, 0u, 0u); }
  __syncthreads();
  if (tid < 224) {  // 4 rows x 28 px x 2 uint4 of group slice
    int r = tid / 56, j = tid - r * 56;
    int px = j >> 1, hh = j & 1;
    int ry = y0 - 1 + r;
    if (ry >= 0 && ry < 28) {
      ((uint4*)apad)[r * 60 + (px + 1) * 2 + hh] =
          ((const uint4*)A2p)[(b * 784 + ry * 28 + px) * 8 + g * 2 + hh];
    }
  }
  __syncthreads();
  if (tid < 120) {  // per-(row,col) popcount
    const uint4* p = ((const uint4*)apad) + tid * 2;
    uint4 A = p[0], B = p[1];
    sp[tid] = __popc(A.x) + __popc(A.y) + __popc(A.z) + __popc(A.w) +
              __popc(B.x) + __popc(B.y) + __popc(B.z) + __popc(B.w);
  }
  __syncthreads();
  if (tid < 56) {  // 3x3 box sums -> BSf (zero pad rows/cols correct)
    int yy = tid / 28, xx = tid - yy * 28;
    int t = sp[yy*30 + xx]     + sp[yy*30 + xx+1]     + sp[yy*30 + xx+2]
          + sp[(yy+1)*30 + xx] + sp[(yy+1)*30 + xx+1] + sp[(yy+1)*30 + xx+2]
          + sp[(yy+2)*30 + xx] + sp[(yy+2)*30 + xx+1] + sp[(yy+2)*30 + xx+2];
    BSf[((b * 28 + y0 + yy) * 28 + xx) * 4 + g] = (float)t;
  }

  uint wr[72];
  const uint4* wb = ((const uint4*)W2p) + oc;
#pragma unroll
  for (int t = 0; t < 9; t++) {
    uint4 w0 = wb[t * 1024];
    uint4 w1 = wb[(9 + t) * 1024];
    wr[t*8+0] = w0.x; wr[t*8+1] = w0.y; wr[t*8+2] = w0.z; wr[t*8+3] = w0.w;
    wr[t*8+4] = w1.x; wr[t*8+5] = w1.y; wr[t*8+6] = w1.z; wr[t*8+7] = w1.w;
  }

  for (int yy = 0; yy < 2; yy++) {
    const int y = y0 + yy;
    u16* Pp = P16 + (size_t)((bb * 28 + y) * 28) * 1024 + oc;
    const uint4* abase = ((const uint4*)apad) + yy * 60;
    int a0 = 0, a1 = 0;
    COLA(0, 1, 0, 0, 0, 0)
    COLA(1, 1, 1, 0, 0, 0)
    COLA(2, 1, 1, 1, 1, 0)
    for (int p = 3; p <= 24; p += 3) {
      COLA(p,     1, 1, 1, 1, (p - 2))
      COLA(p + 1, 1, 1, 1, 1, (p - 1))
      COLA(p + 2, 1, 1, 1, 1, (p))
    }
    COLA(27, 1, 1, 1, 1, 25)
    COLA(28, 0, 1, 1, 1, 26)
    COLA(29, 0, 0, 1, 1, 27)
  }
}

// ---------------- reducer: BN + group-sum + identity + relu ----------------
// grid (28 y, 16 bb); block 256 (thread = c). Phase1: coalesced P reads ->
// LDS [256][29] f32; Phase2: transpose-read, xin add, relu, coalesced writes.
__global__ __launch_bounds__(256) void kRed(
    const u16* __restrict__ P16, const float* __restrict__ BSf,
    const float* __restrict__ bnA2, const float* __restrict__ bbSum,
    const float* __restrict__ xin, float* __restrict__ out, int b0) {
  const int tid = threadIdx.x;
  const int y = blockIdx.x, bb = blockIdx.y, b = b0 + bb;

  __shared__ float vals[256 * 29];

  float cf[4];
#pragma unroll
  for (int g = 0; g < 4; g++) cf[g] = bnA2[g * 256 + tid];
  const float bbs = bbSum[tid];
  const u16* Pp = P16 + (size_t)((bb * 28 + y) * 28) * 1024 + tid;
  const float4* bsp = (const float4*)(BSf + ((b * 28 + y) * 28) * 4);

  for (int x = 0; x < 28; x++) {
    float4 bs = bsp[x];
    float v = bbs;
    float s0 = (float)(int)Pp[x * 1024 + 0];
    float s1 = (float)(int)Pp[x * 1024 + 256];
    float s2 = (float)(int)Pp[x * 1024 + 512];
    float s3 = (float)(int)Pp[x * 1024 + 768];
    v += cf[0] * (2.0f * s0 - bs.x);
    v += cf[1] * (2.0f * s1 - bs.y);
    v += cf[2] * (2.0f * s2 - bs.z);
    v += cf[3] * (2.0f * s3 - bs.w);
    vals[tid * 29 + x] = v;
  }
  __syncthreads();

#pragma unroll
  for (int k = 0; k < 7; k++) {
    int f = tid + 256 * k;        // 0..1791 = 256 c * 7 float4
    int c = f / 7, xq = f - 7 * c;
    int base = ((b * 256 + c) * 28 + y) * 28 + xq * 4;
    float4 xi = *(const float4*)(xin + base);
    float4 o;
    o.x = fmaxf(vals[c * 29 + xq * 4 + 0] + xi.x, 0.0f);
    o.y = fmaxf(vals[c * 29 + xq * 4 + 1] + xi.y, 0.0f);
    o.z = fmaxf(vals[c * 29 + xq * 4 + 2] + xi.z, 0.0f);
    o.w = fmaxf(vals[c * 29 + xq * 4 + 3] + xi.w, 0.0f);
    *(float4*)(out + base) = o;
  }
}

extern "C" void kernel_launch(void* const* d_in, const int* in_sizes, int n_in,
                              void* d_out, int out_size, void* d_ws, size_t ws_size,
                              hipStream_t stream) {
  const float* x   = (const float*)d_in[0];
  const float* w1  = (const float*)d_in[1];
  const float* s1  = (const float*)d_in[2];
  const float* b1  = (const float*)d_in[3];
  const float* m1  = (const float*)d_in[4];
  const float* v1  = (const float*)d_in[5];
  const float* w2  = (const float*)d_in[6];
  const float* s2  = (const float*)d_in[7];
  const float* b2  = (const float*)d_in[8];
  const float* m2  = (const float*)d_in[9];
  const float* v2  = (const float*)d_in[10];
  const float* lam = (const float*)d_in[11];
  float* out = (float*)d_out;

  char* ws = (char*)d_ws;
  uint*  A1p   = (uint*)(ws + 0);          //   802816 B
  uint*  W1p   = (uint*)(ws + 802816);     //   294912 B
  uint*  W2p   = (uint*)(ws + 1097728);    //   294912 B
  uint*  A2p   = (uint*)(ws + 1392640);    //  3211264 B
  float* BSf   = (float*)(ws + 4603904);   //   401408 B
  float* bnA1  = (float*)(ws + 5005312);
  float* bnB1  = (float*)(ws + 5009408);
  float* bnA2  = (float*)(ws + 5013504);
  float* bbSum = (float*)(ws + 5017600);
  u16*   P16   = (u16*)(ws + 5018624);     // 25690112 B (16 batches) -> ~30.7MB

  kPrep<<<4, 256, 0, stream>>>(s1, b1, m1, v1, s2, b2, m2, v2, lam,
                               bnA1, bnB1, bnA2, bbSum);
  kPackX<<<1568, 256, 0, stream>>>(x, A1p);
  kPackW<<<9216, 256, 0, stream>>>(w1, W1p);
  kPackW<<<9216, 256, 0, stream>>>(w2, W2p);
  kConv1<<<dim3(4, 14, 32), 256, 0, stream>>>(A1p, W1p, bnA1, bnB1, A2p);
  for (int b0 = 0; b0 < 32; b0 += 16) {
    kConv2a<<<dim3(4, 14, 16), 256, 0, stream>>>(A2p, W2p, P16, BSf, b0);
    kRed<<<dim3(28, 16), 256, 0, stream>>>(P16, BSf, bnA2, bbSum, x, out, b0);
  }
}